// Round 2
// baseline (2079.375 us; speedup 1.0000x reference)
//
#include <hip/hip_runtime.h>
#include <hip/hip_bf16.h>

#define NN 50000
#define NE 800000

// ---- Pass 1: scatter concat(nfeats[src], efeats[e]) into msum[dst], count degrees.
__global__ __launch_bounds__(256) void k_scatter1(
    const float* __restrict__ nfeats, const float* __restrict__ efeats,
    const int* __restrict__ src, const int* __restrict__ dst,
    float* __restrict__ msum, float* __restrict__ cnt)
{
    int e = blockIdx.x * 4 + (threadIdx.x >> 6);
    int lane = threadIdx.x & 63;
    if (e >= NE) return;
    int s = src[e], d = dst[e];
    float a = nfeats[s * 64 + lane];
    float b = efeats[(size_t)e * 64 + lane];
    atomicAdd(&msum[d * 128 + lane], a);
    atomicAdd(&msum[d * 128 + 64 + lane], b);
    if (lane == 0) atomicAdd(&cnt[d], 1.0f);
}

// ---- Node update: h_out = relu(concat(h_in, msum/max(cnt,1)) @ wa + ba)
// wa is [192,64] row-major; one wave per node, lane = output column.
__global__ __launch_bounds__(256) void k_node(
    const float* __restrict__ hin, const float* __restrict__ msum,
    const float* __restrict__ cnt, const float* __restrict__ wa,
    const float* __restrict__ ba, float* __restrict__ hout)
{
    __shared__ float wsh[192 * 64];
    __shared__ float bsh[64];
    __shared__ float xsh[4][192];
    for (int i = threadIdx.x; i < 192 * 64; i += 256) wsh[i] = wa[i];
    if (threadIdx.x < 64) bsh[threadIdx.x] = ba[threadIdx.x];
    int wv = threadIdx.x >> 6, lane = threadIdx.x & 63;
    for (int base = blockIdx.x * 4; base < NN; base += gridDim.x * 4) {
        __syncthreads();  // covers weight/bias load on iter 0, xsh reuse after
        for (int i = threadIdx.x; i < 4 * 192; i += 256) {
            int w = i / 192, k = i - w * 192;
            int node = base + w;
            float v = 0.f;
            if (node < NN) {
                if (k < 64) {
                    v = hin[(size_t)node * 64 + k];
                } else {
                    float c = cnt[node];
                    c = c > 1.f ? c : 1.f;
                    v = msum[(size_t)node * 128 + (k - 64)] / c;
                }
            }
            xsh[w][k] = v;
        }
        __syncthreads();
        int node = base + wv;
        if (node < NN) {
            float acc = bsh[lane];
            const float* x = xsh[wv];
#pragma unroll 8
            for (int k = 0; k < 192; ++k) acc = fmaf(x[k], wsh[k * 64 + lane], acc);
            acc = acc > 0.f ? acc : 0.f;
            hout[(size_t)node * 64 + lane] = acc;
        }
    }
}

// ---- Edge MLP: h_e = relu(concat(hn[src], hn[dst]) @ we + be).
// SCATTER: also scatter concat(hn[src], h_e) into msum[dst] (layer-2 aggregation,
// h_e0 never materialized in HBM). Else write f32 output.
template <bool SCATTER>
__global__ __launch_bounds__(256) void k_edge(
    const float* __restrict__ hn, const int* __restrict__ src,
    const int* __restrict__ dst, const float* __restrict__ we,
    const float* __restrict__ be, float* __restrict__ msum, float* __restrict__ oute)
{
    __shared__ float wsh[128 * 64];
    __shared__ float bsh[64];
    __shared__ float xsh[4][128];
    for (int i = threadIdx.x; i < 128 * 64; i += 256) wsh[i] = we[i];
    if (threadIdx.x < 64) bsh[threadIdx.x] = be[threadIdx.x];
    int wv = threadIdx.x >> 6, lane = threadIdx.x & 63;
    for (int base = blockIdx.x * 4; base < NE; base += gridDim.x * 4) {
        __syncthreads();
        for (int i = threadIdx.x; i < 4 * 128; i += 256) {
            int w = i >> 7, k = i & 127;
            int e = base + w;
            float v = 0.f;
            if (e < NE) {
                int node = (k < 64) ? src[e] : dst[e];
                v = hn[(size_t)node * 64 + (k & 63)];
            }
            xsh[w][k] = v;
        }
        __syncthreads();
        int e = base + wv;
        if (e < NE) {
            float acc = bsh[lane];
            const float* x = xsh[wv];
#pragma unroll 8
            for (int k = 0; k < 128; ++k) acc = fmaf(x[k], wsh[k * 64 + lane], acc);
            acc = acc > 0.f ? acc : 0.f;
            if (SCATTER) {
                int d = dst[e];
                atomicAdd(&msum[d * 128 + lane], x[lane]);   // hn0[src][lane]
                atomicAdd(&msum[d * 128 + 64 + lane], acc);  // h_e0[lane]
            } else {
                oute[(size_t)e * 64 + lane] = acc;
            }
        }
    }
}

extern "C" void kernel_launch(void* const* d_in, const int* in_sizes, int n_in,
                              void* d_out, int out_size, void* d_ws, size_t ws_size,
                              hipStream_t stream)
{
    const float* nfeats = (const float*)d_in[0];
    const float* efeats = (const float*)d_in[1];
    const int*   src    = (const int*)d_in[2];
    const int*   dst    = (const int*)d_in[3];
    const float* wa0 = (const float*)d_in[4];
    const float* ba0 = (const float*)d_in[5];
    const float* we0 = (const float*)d_in[6];
    const float* be0 = (const float*)d_in[7];
    const float* wa1 = (const float*)d_in[8];
    const float* ba1 = (const float*)d_in[9];
    const float* we1 = (const float*)d_in[10];
    const float* be1 = (const float*)d_in[11];

    float* out_n = (float*)d_out;
    float* out_e = out_n + (size_t)NN * 64;

    char* w = (char*)d_ws;
    float* msum = (float*)w;  w += (size_t)NN * 128 * 4;                  // 25.6 MB
    float* cnt  = (float*)w;  w += ((size_t)NN * 4 + 255) & ~(size_t)255; // 0.2 MB
    float* hn0  = (float*)w;                                              // 12.8 MB

    // Layer 1
    hipMemsetAsync(msum, 0, (size_t)NN * 128 * 4, stream);
    hipMemsetAsync(cnt, 0, (size_t)NN * 4, stream);
    k_scatter1<<<(NE + 3) / 4, 256, 0, stream>>>(nfeats, efeats, src, dst, msum, cnt);
    k_node<<<1250, 256, 0, stream>>>(nfeats, msum, cnt, wa0, ba0, hn0);

    // Layer 2 (edge MLP of layer 1 fused into the scatter)
    hipMemsetAsync(msum, 0, (size_t)NN * 128 * 4, stream);
    k_edge<true><<<4096, 256, 0, stream>>>(hn0, src, dst, we0, be0, msum, nullptr);
    k_node<<<1250, 256, 0, stream>>>(hn0, msum, cnt, wa1, ba1, out_n);

    // Final edge output
    k_edge<false><<<4096, 256, 0, stream>>>(out_n, src, dst, we1, be1, nullptr, out_e);
}

// Round 5
// 1208.902 us; speedup vs baseline: 1.7201x; 1.7201x over previous
//
#include <hip/hip_runtime.h>
#include <hip/hip_bf16.h>

#define NN 50000
#define NE 800000
// NE = 6250 * 128 exactly

typedef float f32x4 __attribute__((ext_vector_type(4)));
typedef __bf16 bf16x8 __attribute__((ext_vector_type(8)));
typedef unsigned short u16x8 __attribute__((ext_vector_type(8)));

__device__ __forceinline__ float bfu_to_f(unsigned short u) {
    union { unsigned int i; float f; } c; c.i = ((unsigned int)u) << 16; return c.f;
}
__device__ __forceinline__ unsigned short f_to_bfu(float f) {
    union { float f; unsigned int i; } c; c.f = f;   // round-to-nearest-even bf16
    unsigned int lsb = (c.i >> 16) & 1;
    c.i += 0x7fffu + lsb;
    return (unsigned short)(c.i >> 16);
}
__device__ __forceinline__ float to_f(float x) { return x; }
__device__ __forceinline__ float to_f(unsigned short x) { return bfu_to_f(x); }

// load 8 contiguous values as 8 bf16 (raw ushort) — from bf16 or f32 source
__device__ __forceinline__ u16x8 load8(const unsigned short* p) { return *(const u16x8*)p; }
__device__ __forceinline__ u16x8 load8(const float* p) {
    f32x4 a = *(const f32x4*)p;
    f32x4 b = *(const f32x4*)(p + 4);
    u16x8 v;
#pragma unroll
    for (int j = 0; j < 4; ++j) { v[j] = f_to_bfu(a[j]); v[4 + j] = f_to_bfu(b[j]); }
    return v;
}

// ---- Pass 1: scatter concat(nfeats[src], efeats[e]) into msum[dst], count degrees.
__global__ __launch_bounds__(256) void k_scatter1(
    const float* __restrict__ nfeats, const float* __restrict__ efeats,
    const int* __restrict__ src, const int* __restrict__ dst,
    float* __restrict__ msum, float* __restrict__ cnt)
{
    int e = blockIdx.x * 4 + (threadIdx.x >> 6);
    int lane = threadIdx.x & 63;
    if (e >= NE) return;
    int s = src[e], d = dst[e];
    float a = nfeats[s * 64 + lane];
    float b = efeats[(size_t)e * 64 + lane];
    atomicAdd(&msum[d * 128 + lane], a);
    atomicAdd(&msum[d * 128 + 64 + lane], b);
    if (lane == 0) atomicAdd(&cnt[d], 1.0f);
}

// ---- Node update: h_out = relu(concat(h_in, msum/max(cnt,1)) @ wa + ba)
// one wave per node, lane = output column. Writes f32 (optional) and/or bf16 (optional).
template <typename TI>
__global__ __launch_bounds__(256) void k_node(
    const TI* __restrict__ hin, const float* __restrict__ msum,
    const float* __restrict__ cnt, const float* __restrict__ wa,
    const float* __restrict__ ba, float* __restrict__ hout,
    unsigned short* __restrict__ obf)
{
    __shared__ float wsh[192 * 64];
    __shared__ float bsh[64];
    __shared__ float xsh[4][192];
    for (int i = threadIdx.x; i < 192 * 64; i += 256) wsh[i] = wa[i];
    if (threadIdx.x < 64) bsh[threadIdx.x] = ba[threadIdx.x];
    int wv = threadIdx.x >> 6, lane = threadIdx.x & 63;
    for (int base = blockIdx.x * 4; base < NN; base += gridDim.x * 4) {
        __syncthreads();
        for (int i = threadIdx.x; i < 4 * 192; i += 256) {
            int w = i / 192, k = i - w * 192;
            int node = base + w;
            float v = 0.f;
            if (node < NN) {
                if (k < 64) {
                    v = to_f(hin[(size_t)node * 64 + k]);
                } else {
                    float c = cnt[node];
                    c = c > 1.f ? c : 1.f;
                    v = msum[(size_t)node * 128 + (k - 64)] / c;
                }
            }
            xsh[w][k] = v;
        }
        __syncthreads();
        int node = base + wv;
        if (node < NN) {
            float acc = bsh[lane];
            const float* x = xsh[wv];
#pragma unroll 8
            for (int k = 0; k < 192; ++k) acc = fmaf(x[k], wsh[k * 64 + lane], acc);
            acc = acc > 0.f ? acc : 0.f;
            if (hout) hout[(size_t)node * 64 + lane] = acc;
            if (obf)  obf[(size_t)node * 64 + lane] = f_to_bfu(acc);
        }
    }
}

// ---- Weight prep: we[128][64] f32 -> WT[64][128] bf16 (transposed), for both layers.
__global__ __launch_bounds__(256) void k_wprep(
    const float* __restrict__ we0, const float* __restrict__ we1,
    unsigned short* __restrict__ wt0, unsigned short* __restrict__ wt1)
{
    int idx = blockIdx.x * 256 + threadIdx.x;
    if (idx >= 2 * 8192) return;
    int w = idx >> 13, i = idx & 8191;
    int n = i >> 7, k = i & 127;
    const float* s = w ? we1 : we0;
    unsigned short* d = w ? wt1 : wt0;
    d[i] = f_to_bfu(s[k * 64 + n]);
}

// ---- Edge MLP via MFMA: h_e = relu(concat(hn[src], hn[dst]) @ we + be).
// Block = 128 edges, 4 waves; each wave: 32 edges x 64 cols (2 m-tiles x 4 n-tiles).
// SCATTER: atomically add concat(hn[src], h_e) into msum[dst] (layer-2 aggregation);
// else write f32 h_e to oute. TI = bf16(ushort) or f32 input (converted in staging).
template <bool SCATTER, typename TI>
__global__ __launch_bounds__(256) void k_edge_mfma(
    const TI* __restrict__ hn, const int* __restrict__ src,
    const int* __restrict__ dst, const unsigned short* __restrict__ wt,
    const float* __restrict__ be, float* __restrict__ msum,
    float* __restrict__ oute)
{
    __shared__ unsigned short xsh[128 * 136];  // [edge][k], pad 136 (272B stride = 2-way, free)
    __shared__ unsigned short wsh[64 * 136];   // [n][k]
    __shared__ int ish[256];                   // [0:128)=src, [128:256)=dst
    int tid = threadIdx.x;
    int e0 = blockIdx.x * 128;

    if (tid < 128) ish[tid] = src[e0 + tid];
    else           ish[tid] = dst[e0 + tid - 128];
    // stage WT: 64 rows x 16 chunks of 8 bf16 = full 128-deep rows
    // (round-3/4 bug: bound 512 with sub=c&7 staged only k<64; k>=64 was garbage -> inf)
#pragma unroll
    for (int c = tid; c < 1024; c += 256) {
        int n = c >> 4, sub = c & 15;
        *(u16x8*)(wsh + n * 136 + sub * 8) = *(const u16x8*)(wt + n * 128 + sub * 8);
    }
    __syncthreads();  // ish ready
#pragma unroll
    for (int c = tid; c < 2048; c += 256) {    // stage X: 128 edges x 2 halves x 8 chunks
        int i = c >> 4, half = (c >> 3) & 1, sub = c & 7;
        int node = ish[half * 128 + i];
        *(u16x8*)(xsh + i * 136 + half * 64 + sub * 8) =
            load8(hn + (size_t)node * 64 + sub * 8);
    }
    __syncthreads();

    int lane = tid & 63, wv = tid >> 6;
    int l15 = lane & 15, quad = lane >> 4;
    f32x4 acc[2][4];
#pragma unroll
    for (int nt = 0; nt < 4; ++nt) {
        float b = be[nt * 16 + l15];
        f32x4 z = {b, b, b, b};
        acc[0][nt] = z; acc[1][nt] = z;
    }
    const unsigned short* xp = xsh + (wv * 32 + l15) * 136 + quad * 8;
    const unsigned short* wp = wsh + l15 * 136 + quad * 8;
#pragma unroll
    for (int kc = 0; kc < 4; ++kc) {
        bf16x8 a0 = *(const bf16x8*)(xp + kc * 32);
        bf16x8 a1 = *(const bf16x8*)(xp + 16 * 136 + kc * 32);
        bf16x8 b0 = *(const bf16x8*)(wp + kc * 32);
        bf16x8 b1 = *(const bf16x8*)(wp + 16 * 136 + kc * 32);
        bf16x8 b2 = *(const bf16x8*)(wp + 32 * 136 + kc * 32);
        bf16x8 b3 = *(const bf16x8*)(wp + 48 * 136 + kc * 32);
        acc[0][0] = __builtin_amdgcn_mfma_f32_16x16x32_bf16(a0, b0, acc[0][0], 0, 0, 0);
        acc[0][1] = __builtin_amdgcn_mfma_f32_16x16x32_bf16(a0, b1, acc[0][1], 0, 0, 0);
        acc[0][2] = __builtin_amdgcn_mfma_f32_16x16x32_bf16(a0, b2, acc[0][2], 0, 0, 0);
        acc[0][3] = __builtin_amdgcn_mfma_f32_16x16x32_bf16(a0, b3, acc[0][3], 0, 0, 0);
        acc[1][0] = __builtin_amdgcn_mfma_f32_16x16x32_bf16(a1, b0, acc[1][0], 0, 0, 0);
        acc[1][1] = __builtin_amdgcn_mfma_f32_16x16x32_bf16(a1, b1, acc[1][1], 0, 0, 0);
        acc[1][2] = __builtin_amdgcn_mfma_f32_16x16x32_bf16(a1, b2, acc[1][2], 0, 0, 0);
        acc[1][3] = __builtin_amdgcn_mfma_f32_16x16x32_bf16(a1, b3, acc[1][3], 0, 0, 0);
    }
    // C/D layout: col = l15 (+nt*16), row-in-tile = quad*4 + r (+mt*16), edge = e0+wv*32+row
    if (SCATTER) {
#pragma unroll
        for (int mt = 0; mt < 2; ++mt)
#pragma unroll
            for (int r = 0; r < 4; ++r) {
                int ei = wv * 32 + mt * 16 + quad * 4 + r;
                int d = ish[128 + ei];
                float* mrow = msum + (size_t)d * 128 + 64;
#pragma unroll
                for (int nt = 0; nt < 4; ++nt) {
                    float v = acc[mt][nt][r];
                    v = v > 0.f ? v : 0.f;
                    atomicAdd(mrow + nt * 16 + l15, v);
                }
            }
        // src-half scatter: msum[dst][0:64] += hn0[src] (from staged bf16)
#pragma unroll 4
        for (int i = 0; i < 32; ++i) {
            int ei = wv * 32 + i;
            int d = ish[128 + ei];
            float v = bfu_to_f(xsh[ei * 136 + lane]);
            atomicAdd(msum + (size_t)d * 128 + lane, v);
        }
    } else {
#pragma unroll
        for (int mt = 0; mt < 2; ++mt)
#pragma unroll
            for (int nt = 0; nt < 4; ++nt)
#pragma unroll
                for (int r = 0; r < 4; ++r) {
                    float v = acc[mt][nt][r];
                    v = v > 0.f ? v : 0.f;
                    int e = e0 + wv * 32 + mt * 16 + quad * 4 + r;
                    oute[(size_t)e * 64 + nt * 16 + l15] = v;
                }
    }
}

extern "C" void kernel_launch(void* const* d_in, const int* in_sizes, int n_in,
                              void* d_out, int out_size, void* d_ws, size_t ws_size,
                              hipStream_t stream)
{
    const float* nfeats = (const float*)d_in[0];
    const float* efeats = (const float*)d_in[1];
    const int*   src    = (const int*)d_in[2];
    const int*   dst    = (const int*)d_in[3];
    const float* wa0 = (const float*)d_in[4];
    const float* ba0 = (const float*)d_in[5];
    const float* we0 = (const float*)d_in[6];
    const float* be0 = (const float*)d_in[7];
    const float* wa1 = (const float*)d_in[8];
    const float* ba1 = (const float*)d_in[9];
    const float* we1 = (const float*)d_in[10];
    const float* be1 = (const float*)d_in[11];

    float* out_n = (float*)d_out;
    float* out_e = out_n + (size_t)NN * 64;

    char* w = (char*)d_ws;
    float* msum = (float*)w;  w += (size_t)NN * 128 * 4;                    // 25.6 MB
    float* cnt  = (float*)w;  w += ((size_t)NN * 4 + 255) & ~(size_t)255;   // 0.2 MB
    unsigned short* hnb = (unsigned short*)w; w += (size_t)NN * 64 * 2;     // 6.4 MB (hn0 in bf16)
    unsigned short* wt0 = (unsigned short*)w; w += 64 * 128 * 2;            // 16 KB
    unsigned short* wt1 = (unsigned short*)w;                               // 16 KB  -> total ~32.2 MB

    // Weight prep for both edge MLPs
    k_wprep<<<64, 256, 0, stream>>>(we0, we1, wt0, wt1);

    // Layer 1
    hipMemsetAsync(msum, 0, (size_t)NN * 128 * 4, stream);
    hipMemsetAsync(cnt, 0, (size_t)NN * 4, stream);
    k_scatter1<<<(NE + 3) / 4, 256, 0, stream>>>(nfeats, efeats, src, dst, msum, cnt);
    k_node<float><<<1250, 256, 0, stream>>>(nfeats, msum, cnt, wa0, ba0, nullptr, hnb);

    // Layer 2 (edge MLP of layer 1 fused into the scatter; h_e0 never in HBM)
    hipMemsetAsync(msum, 0, (size_t)NN * 128 * 4, stream);
    k_edge_mfma<true, unsigned short><<<NE / 128, 256, 0, stream>>>(hnb, src, dst, wt0, be0, msum, nullptr);
    k_node<unsigned short><<<1250, 256, 0, stream>>>(hnb, msum, cnt, wa1, ba1, out_n, nullptr);

    // Final edge output: A-operand staged straight from f32 out_n (bf16 convert in staging)
    k_edge_mfma<false, float><<<NE / 128, 256, 0, stream>>>(out_n, src, dst, wt1, be1, nullptr, out_e);
}